// Round 1
// baseline (713.938 us; speedup 1.0000x reference)
//
#include <hip/hip_runtime.h>
#include <hip/hip_bf16.h>
#include <stdint.h>

typedef __bf16 bf16_t;
typedef __attribute__((ext_vector_type(8))) __bf16 bf16x8;
typedef __attribute__((ext_vector_type(4))) float f32x4;
typedef __attribute__((ext_vector_type(8))) unsigned short u16x8;

#define S_LEN 2048
#define DIM   4096
#define QKVN  6144
#define NHEAD 32
#define HDIM  128

typedef __attribute__((address_space(1))) unsigned int as1_u32;
typedef __attribute__((address_space(3))) unsigned int as3_u32;

__device__ __forceinline__ unsigned short f2bf(float f) {
  unsigned u = __builtin_bit_cast(unsigned, f);
  u += 0x7fffu + ((u >> 16) & 1u);
  return (unsigned short)(u >> 16);
}

// global->LDS direct load, 16B per lane. LDS dest must be linear:
// wave-uniform base + lane*16. Integer-cast idiom (CK-style): LDS generic
// pointer low 32 bits == LDS offset (apertures are 4GB-aligned).
__device__ __forceinline__ void gload_lds16(const void* g, void* l) {
  __builtin_amdgcn_global_load_lds(
      (as1_u32*)(unsigned long long)(uintptr_t)g,
      (as3_u32*)(unsigned int)(uintptr_t)l,
      16, 0, 0);
}

__global__ __launch_bounds__(256) void cvt_kernel(const float* __restrict__ in,
                                                  unsigned short* __restrict__ out,
                                                  int n4) {
  int idx = blockIdx.x * 256 + threadIdx.x;
  int stride = gridDim.x * 256;
  for (int i = idx; i < n4; i += stride) {
    float4 v = ((const float4*)in)[i];
    ushort4 o;
    o.x = f2bf(v.x); o.y = f2bf(v.y); o.z = f2bf(v.z); o.w = f2bf(v.w);
    ((ushort4*)out)[i] = o;
  }
}

// C(M,N) = A(M,K) * B(N,K)^T, bf16 in, f32 acc. 128x128 tile, BK=32,
// 4 waves, each wave 64x64 (4x4 fragments of 16x16x32 MFMA).
template <int OUTF32>
__global__ __launch_bounds__(256) void gemm_bt(const bf16_t* __restrict__ A,
                                               const bf16_t* __restrict__ B,
                                               void* __restrict__ Cout,
                                               int M, int N, int K) {
  __shared__ bf16_t As[128 * 32];
  __shared__ bf16_t Bs[128 * 32];
  const int tid  = threadIdx.x;
  const int lane = tid & 63;
  const int w    = tid >> 6;
  const int wm   = w & 1;
  const int wn   = w >> 1;
  const int lg   = lane >> 4;
  const int lr   = lane & 15;
  const long rowBase = (long)blockIdx.y * 128;
  const long colBase = (long)blockIdx.x * 128;

  f32x4 acc[4][4];
  const f32x4 z4 = {0.f, 0.f, 0.f, 0.f};
#pragma unroll
  for (int i = 0; i < 4; ++i)
#pragma unroll
    for (int j = 0; j < 4; ++j) acc[i][j] = z4;

  const int r0 = tid >> 2;   // staging row (chunk = tid: 4 x 16B chunks per row)
  const int c4 = tid & 3;
  const bf16_t* Ag = A + (rowBase + r0) * (long)K + c4 * 8;
  const bf16_t* Bg = B + (colBase + r0) * (long)K + c4 * 8;
  char* AsB = (char*)As;
  char* BsB = (char*)Bs;

  for (int k0 = 0; k0 < K; k0 += 32) {
    __syncthreads();
    gload_lds16(Ag + k0,                 AsB + tid * 16);
    gload_lds16(Ag + (long)64 * K + k0,  AsB + 4096 + tid * 16);
    gload_lds16(Bg + k0,                 BsB + tid * 16);
    gload_lds16(Bg + (long)64 * K + k0,  BsB + 4096 + tid * 16);
    __syncthreads();

    bf16x8 af[4], bfr[4];
#pragma unroll
    for (int mi = 0; mi < 4; ++mi) {
      int row = wm * 64 + mi * 16 + lr;
      af[mi] = *(const bf16x8*)(AsB + row * 64 + lg * 16);
    }
#pragma unroll
    for (int ni = 0; ni < 4; ++ni) {
      int row = wn * 64 + ni * 16 + lr;
      bfr[ni] = *(const bf16x8*)(BsB + row * 64 + lg * 16);
    }
#pragma unroll
    for (int mi = 0; mi < 4; ++mi)
#pragma unroll
      for (int ni = 0; ni < 4; ++ni)
        acc[mi][ni] = __builtin_amdgcn_mfma_f32_16x16x32_bf16(af[mi], bfr[ni],
                                                              acc[mi][ni], 0, 0, 0);
  }

  const long crow = rowBase + wm * 64;
  const long ccol = colBase + wn * 64;
  if (OUTF32) {
    float* C = (float*)Cout;
#pragma unroll
    for (int mi = 0; mi < 4; ++mi)
#pragma unroll
      for (int j = 0; j < 4; ++j) {
        long row = crow + mi * 16 + lg * 4 + j;
        float* cp = C + row * N + ccol + lr;
#pragma unroll
        for (int ni = 0; ni < 4; ++ni) cp[ni * 16] = acc[mi][ni][j];
      }
  } else {
    unsigned short* C = (unsigned short*)Cout;
#pragma unroll
    for (int mi = 0; mi < 4; ++mi)
#pragma unroll
      for (int j = 0; j < 4; ++j) {
        long row = crow + mi * 16 + lg * 4 + j;
        unsigned short* cp = C + row * N + ccol + lr;
#pragma unroll
        for (int ni = 0; ni < 4; ++ni) cp[ni * 16] = f2bf(acc[mi][ni][j]);
      }
  }
}

// In-place RoPE on bf16 qkv buffer. One thread per (s, head, pair).
// 40 heads: 0..31 = q heads, 32..39 = k heads.
__global__ __launch_bounds__(256) void rope_kernel(unsigned int* __restrict__ qkv32,
                                                   const float* __restrict__ cosb,
                                                   const float* __restrict__ sinb) {
  int t = blockIdx.x * 256 + threadIdx.x;  // total 2048*40*64
  int i  = t & 63;
  int sh = t >> 6;
  int hh = sh % 40;
  int s  = sh / 40;
  int col2 = (hh < 32) ? (hh * 64 + i) : (2048 + (hh - 32) * 64 + i);
  unsigned int* p = qkv32 + (long)s * (QKVN / 2) + col2;
  unsigned int v = *p;
  float tr = __builtin_bit_cast(float, (v & 0xffffu) << 16);
  float ti = __builtin_bit_cast(float, v & 0xffff0000u);
  float c  = cosb[s * 64 + i];
  float sn = sinb[s * 64 + i];
  float orr = tr * c - ti * sn;
  float oi  = tr * sn + ti * c;
  *p = (unsigned int)f2bf(orr) | ((unsigned int)f2bf(oi) << 16);
}

// Flash attention: block = (64 q-rows, 1 head), 4 waves x 16 q-rows each.
// KV tiles of 32 staged in LDS (K XOR-swizzled; V transposed + swizzled).
__global__ __launch_bounds__(256) void attn_kernel(const bf16_t* __restrict__ qkv,
                                                   unsigned short* __restrict__ ob) {
  __shared__ bf16_t Kt[32 * 128];
  __shared__ bf16_t Vt[128 * 32];
  __shared__ bf16_t Pl[4 * 16 * 32];
  const int h  = blockIdx.y;
  const int qb = blockIdx.x * 64;
  const int kh = h >> 2;  // REPEATS = 4
  const int tid = threadIdx.x, lane = tid & 63, w = tid >> 6;
  const int lg = lane >> 4, lr = lane & 15;
  const int qrow0 = qb + w * 16;

  bf16x8 qf[4];
  const bf16_t* qptr = qkv + (long)(qrow0 + lr) * QKVN + h * HDIM + lg * 8;
#pragma unroll
  for (int kk = 0; kk < 4; ++kk) qf[kk] = *(const bf16x8*)(qptr + kk * 32);

  const f32x4 z4 = {0.f, 0.f, 0.f, 0.f};
  f32x4 oacc[8];
#pragma unroll
  for (int c = 0; c < 8; ++c) oacc[c] = z4;
  float m[4]    = {-1e30f, -1e30f, -1e30f, -1e30f};
  float lsum[4] = {0.f, 0.f, 0.f, 0.f};

  const int nkvb = qb / 32 + 2;
  const int wqmax = qrow0 + 15;
  char* KtB = (char*)Kt;
  char* VtB = (char*)Vt;
  char* PlB = (char*)Pl + w * 1024;
  const float scale = 0.08838834764831845f;

  for (int kvb = 0; kvb < nkvb; ++kvb) {
    const int kv0 = kvb * 32;
    __syncthreads();
#pragma unroll
    for (int it = 0; it < 2; ++it) {
      int cch = tid + it * 256;          // 512 chunks of 16B (32 rows x 16)
      int r = cch >> 4, c16 = cch & 15;
      const bf16_t* kg = qkv + (long)(kv0 + r) * QKVN + 4096 + kh * HDIM + c16 * 8;
      u16x8 kval = *(const u16x8*)kg;
      int kb = (r * 256 + c16 * 16) ^ ((r & 7) << 4);
      *(u16x8*)(KtB + kb) = kval;
      const bf16_t* vg = qkv + (long)(kv0 + r) * QKVN + 5120 + kh * HDIM + c16 * 8;
      u16x8 vval = *(const u16x8*)vg;
#pragma unroll
      for (int e = 0; e < 8; ++e) {      // transpose scatter: Vt[hd][kv]
        int hd = c16 * 8 + e;
        int vb = (hd * 64 + r * 2) ^ ((hd & 3) << 4);
        *(unsigned short*)(VtB + vb) = vval[e];
      }
    }
    __syncthreads();
    if (kv0 > wqmax) continue;  // fully masked for this wave (barriers already done)

    // S(16x32) = Q(16x128) * K^T
    f32x4 sf[2];
#pragma unroll
    for (int fi = 0; fi < 2; ++fi) {
      f32x4 a = z4;
      int n = fi * 16 + lr;
      int rb = n * 256, sw = (n & 7) << 4;
#pragma unroll
      for (int kk = 0; kk < 4; ++kk) {
        bf16x8 kf = *(const bf16x8*)(KtB + rb + ((((kk * 4 + lg) * 16)) ^ sw));
        a = __builtin_amdgcn_mfma_f32_16x16x32_bf16(qf[kk], kf, a, 0, 0, 0);
      }
      sf[fi] = a;
    }

    // online softmax (rows: lg*4+j, cols: lane group of 16)
    float sc_arr[4];
#pragma unroll
    for (int j = 0; j < 4; ++j) {
      int qrow = qrow0 + lg * 4 + j;
      float s0 = sf[0][j] * scale;
      float s1 = sf[1][j] * scale;
      if (kv0 + lr > qrow)      s0 = -1e9f;
      if (kv0 + 16 + lr > qrow) s1 = -1e9f;
      float mx = fmaxf(s0, s1);
      mx = fmaxf(mx, __shfl_xor(mx, 1));
      mx = fmaxf(mx, __shfl_xor(mx, 2));
      mx = fmaxf(mx, __shfl_xor(mx, 4));
      mx = fmaxf(mx, __shfl_xor(mx, 8));
      float mn = fmaxf(m[j], mx);
      float p0 = __expf(s0 - mn);
      float p1 = __expf(s1 - mn);
      float ps = p0 + p1;
      ps += __shfl_xor(ps, 1);
      ps += __shfl_xor(ps, 2);
      ps += __shfl_xor(ps, 4);
      ps += __shfl_xor(ps, 8);
      float sc = __expf(m[j] - mn);
      lsum[j] = lsum[j] * sc + ps;
      m[j] = mn;
      sc_arr[j] = sc;
      int row = lg * 4 + j;
      int swp = (row & 3) << 4;
      *(unsigned short*)(PlB + row * 64 + ((lr * 2) ^ swp))        = f2bf(p0);
      *(unsigned short*)(PlB + row * 64 + (((16 + lr) * 2) ^ swp)) = f2bf(p1);
    }
#pragma unroll
    for (int c = 0; c < 8; ++c) {
#pragma unroll
      for (int j = 0; j < 4; ++j) oacc[c][j] *= sc_arr[j];
    }
    // O(16x128) += P(16x32) * V(32x128)
    int psw = (lr & 3) << 4;
    bf16x8 pf = *(const bf16x8*)(PlB + lr * 64 + ((lg * 16) ^ psw));
#pragma unroll
    for (int c = 0; c < 8; ++c) {
      int hd = c * 16 + lr;
      bf16x8 vf = *(const bf16x8*)(VtB + hd * 64 + ((lg * 16) ^ ((hd & 3) << 4)));
      oacc[c] = __builtin_amdgcn_mfma_f32_16x16x32_bf16(pf, vf, oacc[c], 0, 0, 0);
    }
  }

  float rl[4];
#pragma unroll
  for (int j = 0; j < 4; ++j) rl[j] = 1.f / lsum[j];
#pragma unroll
  for (int c = 0; c < 8; ++c)
#pragma unroll
    for (int j = 0; j < 4; ++j) {
      long row = qrow0 + lg * 4 + j;
      ob[row * 4096 + h * 128 + c * 16 + lr] = f2bf(oacc[c][j] * rl[j]);
    }
}

extern "C" void kernel_launch(void* const* d_in, const int* in_sizes, int n_in,
                              void* d_out, int out_size, void* d_ws, size_t ws_size,
                              hipStream_t stream) {
  const float* x  = (const float*)d_in[0];
  const float* wq = (const float*)d_in[1];
  const float* wk = (const float*)d_in[2];
  const float* wv = (const float*)d_in[3];
  const float* wo = (const float*)d_in[4];
  const float* fc = (const float*)d_in[5];
  const float* fs = (const float*)d_in[6];

  char* ws = (char*)d_ws;
  bf16_t* xb    = (bf16_t*)(ws + 0);          // 2048x4096      (16 MB)
  bf16_t* wqkvb = (bf16_t*)(ws + 16777216);   // 6144x4096      (48 MB)
  bf16_t* wob   = (bf16_t*)(ws + 67108864);   // 4096x4096      (32 MB)
  bf16_t* qkv   = (bf16_t*)(ws + 100663296);  // 2048x6144      (24 MB)
  bf16_t* ob    = (bf16_t*)(ws + 125829120);  // 2048x4096      (16 MB)

  cvt_kernel<<<2048, 256, 0, stream>>>(x,  (unsigned short*)xb,                  (2048 * 4096) / 4);
  cvt_kernel<<<2048, 256, 0, stream>>>(wq, (unsigned short*)wqkvb,               (4096 * 4096) / 4);
  cvt_kernel<<<1024, 256, 0, stream>>>(wk, (unsigned short*)(wqkvb + 4096 * 4096), (1024 * 4096) / 4);
  cvt_kernel<<<1024, 256, 0, stream>>>(wv, (unsigned short*)(wqkvb + 5120 * 4096), (1024 * 4096) / 4);
  cvt_kernel<<<2048, 256, 0, stream>>>(wo, (unsigned short*)wob,                 (4096 * 4096) / 4);

  gemm_bt<0><<<dim3(48, 16), 256, 0, stream>>>(xb, wqkvb, qkv, 2048, 6144, 4096);
  rope_kernel<<<20480, 256, 0, stream>>>((unsigned int*)qkv, fc, fs);
  attn_kernel<<<dim3(32, 32), 256, 0, stream>>>(qkv, (unsigned short*)ob);
  gemm_bt<1><<<dim3(32, 16), 256, 0, stream>>>(ob, wob, d_out, 2048, 4096, 4096);
}

// Round 2
// 395.106 us; speedup vs baseline: 1.8070x; 1.8070x over previous
//
#include <hip/hip_runtime.h>
#include <hip/hip_bf16.h>
#include <stdint.h>

typedef __bf16 bf16_t;
typedef __attribute__((ext_vector_type(8))) __bf16 bf16x8;
typedef __attribute__((ext_vector_type(4))) float f32x4;
typedef __attribute__((ext_vector_type(8))) unsigned short u16x8;

#define S_LEN 2048
#define DIM   4096
#define QKVN  6144
#define NHEAD 32
#define HDIM  128

typedef __attribute__((address_space(1))) unsigned int as1_u32;
typedef __attribute__((address_space(3))) unsigned int as3_u32;

__device__ __forceinline__ unsigned short f2bf(float f) {
  unsigned u = __builtin_bit_cast(unsigned, f);
  u += 0x7fffu + ((u >> 16) & 1u);
  return (unsigned short)(u >> 16);
}

__device__ __forceinline__ void gload_lds16(const void* g, void* l) {
  __builtin_amdgcn_global_load_lds(
      (as1_u32*)(unsigned long long)(uintptr_t)g,
      (as3_u32*)(unsigned int)(uintptr_t)l,
      16, 0, 0);
}

__global__ __launch_bounds__(256) void cvt_kernel(const float* __restrict__ in,
                                                  unsigned short* __restrict__ out,
                                                  int n4) {
  int idx = blockIdx.x * 256 + threadIdx.x;
  int stride = gridDim.x * 256;
  for (int i = idx; i < n4; i += stride) {
    float4 v = ((const float4*)in)[i];
    ushort4 o;
    o.x = f2bf(v.x); o.y = f2bf(v.y); o.z = f2bf(v.z); o.w = f2bf(v.w);
    ((ushort4*)out)[i] = o;
  }
}

// C(M,N) = A(M,K) * B(N,K)^T, bf16 in, f32 acc. 128x128 tile, BK=32,
// 4 waves, each wave 64x64 (4x4 fragments of 16x16x32 MFMA).
template <int OUTF32>
__global__ __launch_bounds__(256) void gemm_bt(const bf16_t* __restrict__ A,
                                               const bf16_t* __restrict__ B,
                                               void* __restrict__ Cout,
                                               int M, int N, int K) {
  __shared__ bf16_t As[128 * 32];
  __shared__ bf16_t Bs[128 * 32];
  const int tid  = threadIdx.x;
  const int lane = tid & 63;
  const int w    = tid >> 6;
  const int wm   = w & 1;
  const int wn   = w >> 1;
  const int lg   = lane >> 4;
  const int lr   = lane & 15;
  const long rowBase = (long)blockIdx.y * 128;
  const long colBase = (long)blockIdx.x * 128;

  f32x4 acc[4][4];
  const f32x4 z4 = {0.f, 0.f, 0.f, 0.f};
#pragma unroll
  for (int i = 0; i < 4; ++i)
#pragma unroll
    for (int j = 0; j < 4; ++j) acc[i][j] = z4;

  const int r0 = tid >> 2;
  const int c4 = tid & 3;
  const bf16_t* Ag = A + (rowBase + r0) * (long)K + c4 * 8;
  const bf16_t* Bg = B + (colBase + r0) * (long)K + c4 * 8;
  char* AsB = (char*)As;
  char* BsB = (char*)Bs;

  for (int k0 = 0; k0 < K; k0 += 32) {
    __syncthreads();
    gload_lds16(Ag + k0,                 AsB + tid * 16);
    gload_lds16(Ag + (long)64 * K + k0,  AsB + 4096 + tid * 16);
    gload_lds16(Bg + k0,                 BsB + tid * 16);
    gload_lds16(Bg + (long)64 * K + k0,  BsB + 4096 + tid * 16);
    __syncthreads();

    bf16x8 af[4], bfr[4];
#pragma unroll
    for (int mi = 0; mi < 4; ++mi) {
      int row = wm * 64 + mi * 16 + lr;
      af[mi] = *(const bf16x8*)(AsB + row * 64 + lg * 16);
    }
#pragma unroll
    for (int ni = 0; ni < 4; ++ni) {
      int row = wn * 64 + ni * 16 + lr;
      bfr[ni] = *(const bf16x8*)(BsB + row * 64 + lg * 16);
    }
#pragma unroll
    for (int mi = 0; mi < 4; ++mi)
#pragma unroll
      for (int ni = 0; ni < 4; ++ni)
        acc[mi][ni] = __builtin_amdgcn_mfma_f32_16x16x32_bf16(af[mi], bfr[ni],
                                                              acc[mi][ni], 0, 0, 0);
  }

  const long crow = rowBase + wm * 64;
  const long ccol = colBase + wn * 64;
  if (OUTF32) {
    float* C = (float*)Cout;
#pragma unroll
    for (int mi = 0; mi < 4; ++mi)
#pragma unroll
      for (int j = 0; j < 4; ++j) {
        long row = crow + mi * 16 + lg * 4 + j;
        float* cp = C + row * N + ccol + lr;
#pragma unroll
        for (int ni = 0; ni < 4; ++ni) cp[ni * 16] = acc[mi][ni][j];
      }
  } else {
    unsigned short* C = (unsigned short*)Cout;
#pragma unroll
    for (int mi = 0; mi < 4; ++mi)
#pragma unroll
      for (int j = 0; j < 4; ++j) {
        long row = crow + mi * 16 + lg * 4 + j;
        unsigned short* cp = C + row * N + ccol + lr;
#pragma unroll
        for (int ni = 0; ni < 4; ++ni) cp[ni * 16] = f2bf(acc[mi][ni][j]);
      }
  }
}

// In-place RoPE on bf16 qkv buffer (q heads 0..31, k heads 32..39).
__global__ __launch_bounds__(256) void rope_kernel(unsigned int* __restrict__ qkv32,
                                                   const float* __restrict__ cosb,
                                                   const float* __restrict__ sinb) {
  int t = blockIdx.x * 256 + threadIdx.x;
  int i  = t & 63;
  int sh = t >> 6;
  int hh = sh % 40;
  int s  = sh / 40;
  int col2 = (hh < 32) ? (hh * 64 + i) : (2048 + (hh - 32) * 64 + i);
  unsigned int* p = qkv32 + (long)s * (QKVN / 2) + col2;
  unsigned int v = *p;
  float tr = __builtin_bit_cast(float, (v & 0xffffu) << 16);
  float ti = __builtin_bit_cast(float, v & 0xffff0000u);
  float c  = cosb[s * 64 + i];
  float sn = sinb[s * 64 + i];
  float orr = tr * c - ti * sn;
  float oi  = tr * sn + ti * c;
  *p = (unsigned int)f2bf(orr) | ((unsigned int)f2bf(oi) << 16);
}

// V transpose: vT[kh][hd][s] from qkv[s][5120 + kh*128 + hd].
// grid (8, 128), block 256: tid = (sg<<7) | hd; s0 = by*16 + sg*8.
__global__ __launch_bounds__(256) void vtrans_kernel(const bf16_t* __restrict__ qkv,
                                                     bf16_t* __restrict__ vT) {
  const int kh = blockIdx.x;
  const int hd = threadIdx.x & 127;
  const int s0 = blockIdx.y * 16 + (threadIdx.x >> 7) * 8;
  u16x8 v;
#pragma unroll
  for (int e = 0; e < 8; ++e)
    v[e] = *(const unsigned short*)(qkv + (long)(s0 + e) * QKVN + 5120 + kh * HDIM + hd);
  *(u16x8*)(vT + ((long)kh * HDIM + hd) * S_LEN + s0) = v;
}

// Flash attention v2: block = (64 q-rows, 1 head), 4 waves x 16 q-rows.
// KVBLK=64. K [64][128] and V^T [128][64] staged via global_load_lds with
// source-chunk XOR swizzle (LDS dest linear); reads XOR the same involution.
__global__ __launch_bounds__(256) void attn_kernel(const bf16_t* __restrict__ qkv,
                                                   const bf16_t* __restrict__ vT,
                                                   unsigned short* __restrict__ ob) {
  __shared__ bf16_t Kt[64 * 128];   // 16 KB, swizzled
  __shared__ bf16_t Vt[128 * 64];   // 16 KB, swizzled (holds V^T)
  __shared__ bf16_t Pl[4 * 16 * 64];// 8 KB, per-wave P, swizzled
  const int h  = blockIdx.x;            // head, uniform work across dispatch round
  const int qi = 31 - blockIdx.y;       // heavy blocks dispatched first
  const int qb = qi * 64;
  const int kh = h >> 2;                // REPEATS = 4
  const int tid = threadIdx.x, lane = tid & 63, w = tid >> 6;
  const int lg = lane >> 4, lr = lane & 15;
  const int qrow0 = qb + w * 16;

  bf16x8 qf[4];
  const bf16_t* qptr = qkv + (long)(qrow0 + lr) * QKVN + h * HDIM + lg * 8;
#pragma unroll
  for (int kk = 0; kk < 4; ++kk) qf[kk] = *(const bf16x8*)(qptr + kk * 32);

  const f32x4 z4 = {0.f, 0.f, 0.f, 0.f};
  f32x4 oacc[8];
#pragma unroll
  for (int c = 0; c < 8; ++c) oacc[c] = z4;
  float m[4]    = {-1e30f, -1e30f, -1e30f, -1e30f};
  float lsum[4] = {0.f, 0.f, 0.f, 0.f};

  char* KtB = (char*)Kt;
  char* VtB = (char*)Vt;
  char* PlB = (char*)Pl + w * 2048;
  const float scale = 0.08838834764831845f;
  const int ntiles = qi + 1;

  for (int t = 0; t < ntiles; ++t) {
    const int kv0 = t * 64;
    __syncthreads();
    // K tile: 64 rows x 128 hd = 1024 chunks of 16B; source chunk XOR (r&7).
#pragma unroll
    for (int it = 0; it < 4; ++it) {
      int cch = tid + it * 256;
      int r = cch >> 4, c = cch & 15;
      const bf16_t* src = qkv + (long)(kv0 + r) * QKVN + 4096 + kh * HDIM
                          + ((c ^ (r & 7)) * 8);
      gload_lds16(src, KtB + cch * 16);
    }
    // V^T tile: 128 rows(hd) x 64 kv = 1024 chunks; source chunk XOR (hd&7).
#pragma unroll
    for (int it = 0; it < 4; ++it) {
      int cch = tid + it * 256;
      int hd = cch >> 3, c = cch & 7;
      const bf16_t* src = vT + ((long)kh * HDIM + hd) * S_LEN + kv0
                          + ((c ^ (hd & 7)) * 8);
      gload_lds16(src, VtB + cch * 16);
    }
    __syncthreads();

    // S(16x64) = Q(16x128) * K^T : 4 col-fragments x 4 k-slices
    f32x4 sf[4];
#pragma unroll
    for (int f = 0; f < 4; ++f) {
      f32x4 a = z4;
      int n = f * 16 + lr;
      int rb = n * 256, sw = (n & 7) << 4;
#pragma unroll
      for (int kk = 0; kk < 4; ++kk) {
        bf16x8 kf = *(const bf16x8*)(KtB + rb + (((kk * 4 + lg) * 16) ^ sw));
        a = __builtin_amdgcn_mfma_f32_16x16x32_bf16(qf[kk], kf, a, 0, 0, 0);
      }
      sf[f] = a;
    }

    // online softmax over 64 cols (rows: lg*4+j; cols: f*16+lr)
    float sc_arr[4];
#pragma unroll
    for (int j = 0; j < 4; ++j) {
      int qrow = qrow0 + lg * 4 + j;
      float sv[4];
#pragma unroll
      for (int f = 0; f < 4; ++f) {
        float s = sf[f][j] * scale;
        if (kv0 + f * 16 + lr > qrow) s = -1e9f;
        sv[f] = s;
      }
      float mx = fmaxf(fmaxf(sv[0], sv[1]), fmaxf(sv[2], sv[3]));
      mx = fmaxf(mx, __shfl_xor(mx, 1));
      mx = fmaxf(mx, __shfl_xor(mx, 2));
      mx = fmaxf(mx, __shfl_xor(mx, 4));
      mx = fmaxf(mx, __shfl_xor(mx, 8));
      float mn = fmaxf(m[j], mx);
      float p[4];
#pragma unroll
      for (int f = 0; f < 4; ++f) p[f] = __expf(sv[f] - mn);
      float ps = (p[0] + p[1]) + (p[2] + p[3]);
      ps += __shfl_xor(ps, 1);
      ps += __shfl_xor(ps, 2);
      ps += __shfl_xor(ps, 4);
      ps += __shfl_xor(ps, 8);
      float sc = __expf(m[j] - mn);
      lsum[j] = lsum[j] * sc + ps;
      m[j] = mn;
      sc_arr[j] = sc;
      int row = lg * 4 + j;
      int swp = (row & 7) << 4;
#pragma unroll
      for (int f = 0; f < 4; ++f)
        *(unsigned short*)(PlB + row * 128 + (((f * 16 + lr) * 2) ^ swp)) = f2bf(p[f]);
    }
#pragma unroll
    for (int c = 0; c < 8; ++c)
#pragma unroll
      for (int j = 0; j < 4; ++j) oacc[c][j] *= sc_arr[j];

    // O(16x128) += P(16x64) * V(64x128)
    bf16x8 pfr[2];
#pragma unroll
    for (int kk = 0; kk < 2; ++kk)
      pfr[kk] = *(const bf16x8*)(PlB + lr * 128 + (((kk * 4 + lg) * 16) ^ ((lr & 7) << 4)));
#pragma unroll
    for (int c = 0; c < 8; ++c) {
      int hd = c * 16 + lr;
      int rb = hd * 128, sw = (hd & 7) << 4;
#pragma unroll
      for (int kk = 0; kk < 2; ++kk) {
        bf16x8 vf = *(const bf16x8*)(VtB + rb + (((kk * 4 + lg) * 16) ^ sw));
        oacc[c] = __builtin_amdgcn_mfma_f32_16x16x32_bf16(pfr[kk], vf, oacc[c], 0, 0, 0);
      }
    }
  }

  float rl[4];
#pragma unroll
  for (int j = 0; j < 4; ++j) rl[j] = 1.f / lsum[j];
#pragma unroll
  for (int c = 0; c < 8; ++c)
#pragma unroll
    for (int j = 0; j < 4; ++j) {
      long row = qrow0 + lg * 4 + j;
      ob[row * 4096 + h * 128 + c * 16 + lr] = f2bf(oacc[c][j] * rl[j]);
    }
}

extern "C" void kernel_launch(void* const* d_in, const int* in_sizes, int n_in,
                              void* d_out, int out_size, void* d_ws, size_t ws_size,
                              hipStream_t stream) {
  const float* x  = (const float*)d_in[0];
  const float* wq = (const float*)d_in[1];
  const float* wk = (const float*)d_in[2];
  const float* wv = (const float*)d_in[3];
  const float* wo = (const float*)d_in[4];
  const float* fc = (const float*)d_in[5];
  const float* fs = (const float*)d_in[6];

  char* ws = (char*)d_ws;
  bf16_t* xb    = (bf16_t*)(ws + 0);          // 2048x4096 (dead after gemm1)
  bf16_t* wqkvb = (bf16_t*)(ws + 16777216);   // 6144x4096
  bf16_t* wob   = (bf16_t*)(ws + 67108864);   // 4096x4096
  bf16_t* qkv   = (bf16_t*)(ws + 100663296);  // 2048x6144
  bf16_t* ob    = (bf16_t*)(ws + 125829120);  // 2048x4096
  bf16_t* vT    = (bf16_t*)(ws + 0);          // 8x128x2048 (4 MB, reuses xb)

  cvt_kernel<<<2048, 256, 0, stream>>>(x,  (unsigned short*)xb,                    (2048 * 4096) / 4);
  cvt_kernel<<<2048, 256, 0, stream>>>(wq, (unsigned short*)wqkvb,                 (4096 * 4096) / 4);
  cvt_kernel<<<1024, 256, 0, stream>>>(wk, (unsigned short*)(wqkvb + 4096 * 4096), (1024 * 4096) / 4);
  cvt_kernel<<<1024, 256, 0, stream>>>(wv, (unsigned short*)(wqkvb + 5120 * 4096), (1024 * 4096) / 4);
  cvt_kernel<<<2048, 256, 0, stream>>>(wo, (unsigned short*)wob,                   (4096 * 4096) / 4);

  gemm_bt<0><<<dim3(48, 16), 256, 0, stream>>>(xb, wqkvb, qkv, 2048, 6144, 4096);
  vtrans_kernel<<<dim3(8, 128), 256, 0, stream>>>(qkv, vT);
  rope_kernel<<<20480, 256, 0, stream>>>((unsigned int*)qkv, fc, fs);
  attn_kernel<<<dim3(32, 32), 256, 0, stream>>>(qkv, vT, (unsigned short*)ob);
  gemm_bt<1><<<dim3(32, 16), 256, 0, stream>>>(ob, wob, d_out, 2048, 4096, 4096);
}